// Round 21
// baseline (115.730 us; speedup 1.0000x reference)
//
#include <hip/hip_runtime.h>
#include <stdint.h>

#define NLVL 16
#define TSIZE 16384
#define HW 512

typedef float vfloat4 __attribute__((ext_vector_type(4)));  // native vec for nt-store

__constant__ int c_n[NLVL] = {16,20,25,32,40,50,64,80,101,128,161,203,256,322,406,512};

__device__ __forceinline__ uint32_t pkmax(uint32_t a, uint32_t b) {
    uint32_t r;
    asm("v_pk_max_u16 %0, %1, %2" : "=v"(r) : "v"(a), "v"(b));
    return r;
}

// V stride: pad cols to multiple of 4 with stride % 8 == 4 (banks spread over
// rows; avoids the stride%32==0 16-way conflict class).
constexpr int padS(int w) {
    int s = (w + 3) & ~3;
    if (s % 8 == 0) s += 4;
    return s;
}

// P sliding-window (width KK) maxima: o[j] = max(e[j..j+KK-1]).
// Block van Herk: per KK-output block, suffix array (KK regs) + running max.
// All indices compile-time; liveness ~KK.
template<int KK, int P, int NE>
__device__ __forceinline__ void winmax(const uint32_t (&e)[NE], uint32_t (&o)[P]) {
    static_assert(NE >= P + KK - 1, "window overrun");
    if constexpr (KK == 1) {
#pragma unroll
        for (int j = 0; j < P; ++j) o[j] = e[j];
    } else {
        constexpr int NB = (P + KK - 1) / KK;
#pragma unroll
        for (int bb = 0; bb < NB; ++bb) {
            const int j0 = bb * KK;
            uint32_t sfx[KK];
            sfx[KK - 1] = e[j0 + KK - 1];
#pragma unroll
            for (int t = KK - 2; t >= 0; --t) sfx[t] = pkmax(e[j0 + t], sfx[t + 1]);
            o[j0] = sfx[0];                      // window == the sfx segment
            uint32_t run = 0;
#pragma unroll
            for (int d = 1; d < KK; ++d) {
                if (j0 + d < P) {
                    run = (d == 1) ? e[j0 + KK] : pkmax(run, e[j0 + KK + d - 1]);
                    o[j0 + d] = pkmax(sfx[d], run);
                }
            }
        }
    }
}

// Vertical chain for one level inside a shared-load group: pack loaded floats
// with this level's nf, window-max, write to its V plane at shifted (dr,dc).
template<int K1, int Ki, int Si>
__device__ __forceinline__ void vchain(const float (&v0)[K1 + 8], const float (&v1)[K1 + 8],
                                       const float nfi, uint32_t* __restrict__ Vi,
                                       const int c, const int r0,
                                       const int dri, const int dci) {
    constexpr int Pi = K1 - Ki + 9;
    uint32_t e[K1 + 8];
#pragma unroll
    for (int t = 0; t < K1 + 8; ++t)
        e[t] = (uint32_t)(v0[t] * nfi) | ((uint32_t)(v1[t] * nfi) << 16);
    uint32_t o[Pi];
    winmax<Ki, Pi, K1 + 8>(e, o);
    const int ci = c - dci;
    if (ci >= 0 && ci < Si) {
#pragma unroll
        for (int j = 0; j < Pi; ++j) {
            const int i2 = r0 + j - dri;
            if (i2 >= 0 && i2 <= 32) Vi[i2 * Si + ci] = o[j];   // wave dups: same value
        }
    }
}

// Horizontal window-max + hash + gather: V[33][S] packed -> feat[33][34].
template<int K, int S>
__device__ __forceinline__ void phaseB(const uint32_t* __restrict__ V,
                                       float2* __restrict__ feat,
                                       const float2* __restrict__ tb, const int tid) {
    if (tid < 99) {
        const int i = tid / 3, g = tid % 3;
        constexpr int NCH = (K + 14) >> 2;
        uint32_t f[NCH * 4];
        const uint4* rp = (const uint4*)(V + i * S + 12 * g);    // 16B aligned (S%4==0)
#pragma unroll
        for (int cc = 0; cc < NCH; ++cc) {
            const uint4 q = rp[cc];
            f[4*cc] = q.x; f[4*cc+1] = q.y; f[4*cc+2] = q.z; f[4*cc+3] = q.w;
        }
        uint32_t wm[12];
        winmax<K, 12, NCH * 4>(f, wm);
#pragma unroll
        for (int d = 0; d < 12; ++d) {
            const int j = 12 * g + d;
            if (j < 33) {
                const uint32_t m = wm[d];
                const uint32_t idx = ((m & 0xFFFFu) ^ ((m >> 16) * 2654435761u)) & (TSIZE - 1);
                feat[i * 34 + j] = tb[idx];
            }
        }
    }
}

// Bilinear interp from feat + nt stores.
template<int K>
__device__ __forceinline__ void phaseC(const float2* __restrict__ feat,
                                       float* __restrict__ ob,
                                       const int rmin, const int cmin,
                                       const int tx0, const int ty0, const int tid) {
    constexpr int gh = 513 - K;
    constexpr float s = (float)gh * (1.0f / 512.0f);
    const int bty = tid >> 5, btx = tid & 31;
    const int xo = tx0 + btx;
    const float sxf = ((float)xo + 0.5f) * s - 0.5f;
    const float fxf = floorf(sxf);
    const float wx = sxf - fxf;
    const int x0i = (int)fxf;
    const int jx0 = min(max(x0i, 0), gh - 1) - cmin;
    const int jx1 = min(max(x0i + 1, 0), gh - 1) - cmin;
    for (int oy = bty; oy < 32; oy += 8) {
        const int y = ty0 + oy;
        const float syf = ((float)y + 0.5f) * s - 0.5f;
        const float fyf = floorf(syf);
        const float wy = syf - fyf;
        const int y0i = (int)fyf;
        const int iy0 = min(max(y0i, 0), gh - 1) - rmin;
        const int iy1 = min(max(y0i + 1, 0), gh - 1) - rmin;
        const float2 f00 = feat[iy0 * 34 + jx0], f01 = feat[iy0 * 34 + jx1];
        const float2 f10 = feat[iy1 * 34 + jx0], f11 = feat[iy1 * 34 + jx1];
        const float w11 = wy * wx;
        const float w10 = wy - w11;
        const float w01 = wx - w11;
        const float w00 = 1.0f - wy - wx + w11;
        const float c0 = f00.x * w00 + f01.x * w01 + f10.x * w10 + f11.x * w11;
        const float c1 = f00.y * w00 + f01.y * w01 + f10.y * w10 + f11.y * w11;
        const size_t o = (size_t)y * HW + xo;
        __builtin_nontemporal_store(c0, &ob[o]);
        __builtin_nontemporal_store(c1, &ob[o + (size_t)HW * HW]);
    }
}

// FOUR levels (K1 > K2 > K3 > K4 windows) from ONE loaded register strip.
// Level-i grid shift (dr_i, dc_i in [0, K1-K_i]) absorbed by computing
// K1-K_i+9 window starts and writing LDS at shifted positions.
template<int K1, int K2, int K3, int K4>
__device__ __forceinline__ void do_quad(
        const int l1, const int l2, const int l3, const int l4,
        const int b, const int tx0, const int ty0,
        const float* __restrict__ x, const float* __restrict__ table,
        float* __restrict__ out, uint32_t* lds) {
    constexpr int S1 = padS(32 + K1), S2 = padS(32 + K2);
    constexpr int S3 = padS(32 + K3), S4 = padS(32 + K4);
    constexpr float s1 = (float)(513 - K1) * (1.0f / 512.0f);
    constexpr float s2 = (float)(513 - K2) * (1.0f / 512.0f);
    constexpr float s3 = (float)(513 - K3) * (1.0f / 512.0f);
    constexpr float s4 = (float)(513 - K4) * (1.0f / 512.0f);
    const int tid = threadIdx.x;

    uint32_t* V1 = lds;
    uint32_t* V2 = V1 + 33 * S1;
    uint32_t* V3 = V2 + 33 * S2;
    uint32_t* V4 = V3 + 33 * S3;
    float2*  feat = (float2*)(V4 + 33 * S4);

    const float* xb0 = x + (size_t)b * 2 * HW * HW;
    const float* xb1 = xb0 + HW * HW;

    const int rmin1 = max((int)floorf(((float)ty0 + 0.5f) * s1 - 0.5f), 0);
    const int cmin1 = max((int)floorf(((float)tx0 + 0.5f) * s1 - 0.5f), 0);
    const int rmin2 = max((int)floorf(((float)ty0 + 0.5f) * s2 - 0.5f), 0);
    const int cmin2 = max((int)floorf(((float)tx0 + 0.5f) * s2 - 0.5f), 0);
    const int rmin3 = max((int)floorf(((float)ty0 + 0.5f) * s3 - 0.5f), 0);
    const int cmin3 = max((int)floorf(((float)tx0 + 0.5f) * s3 - 0.5f), 0);
    const int rmin4 = max((int)floorf(((float)ty0 + 0.5f) * s4 - 0.5f), 0);
    const int cmin4 = max((int)floorf(((float)tx0 + 0.5f) * s4 - 0.5f), 0);

    // ---- phase A: load ONCE, four packed van-Herk chains ----
    {
        const int wv = __builtin_amdgcn_readfirstlane(tid >> 6);
        const int c  = tid & 63;
        const int r0 = 8 * wv;
        const int xx = min(cmin1 + c, HW - 1);
        const int ybase = rmin1 + r0;
        float v0[K1 + 8], v1[K1 + 8];
#pragma unroll
        for (int t = 0; t < K1 + 8; ++t) {
            const int yy = min(ybase + t, HW - 1);
            v0[t] = (xb0 + yy * HW)[xx];
            v1[t] = (xb1 + yy * HW)[xx];
        }
        vchain<K1, K1, S1>(v0, v1, (float)c_n[l1], V1, c, r0, 0, 0);
        vchain<K1, K2, S2>(v0, v1, (float)c_n[l2], V2, c, r0, rmin2 - rmin1, cmin2 - cmin1);
        vchain<K1, K3, S3>(v0, v1, (float)c_n[l3], V3, c, r0, rmin3 - rmin1, cmin3 - cmin1);
        vchain<K1, K4, S4>(v0, v1, (float)c_n[l4], V4, c, r0, rmin4 - rmin1, cmin4 - cmin1);
    }
    __syncthreads();

    phaseB<K1, S1>(V1, feat, (const float2*)table + (size_t)l1 * TSIZE, tid);
    __syncthreads();
    phaseC<K1>(feat, out + ((size_t)b * 32 + l1 * 2) * HW * HW, rmin1, cmin1, tx0, ty0, tid);
    __syncthreads();
    phaseB<K2, S2>(V2, feat, (const float2*)table + (size_t)l2 * TSIZE, tid);
    __syncthreads();
    phaseC<K2>(feat, out + ((size_t)b * 32 + l2 * 2) * HW * HW, rmin2, cmin2, tx0, ty0, tid);
    __syncthreads();
    phaseB<K3, S3>(V3, feat, (const float2*)table + (size_t)l3 * TSIZE, tid);
    __syncthreads();
    phaseC<K3>(feat, out + ((size_t)b * 32 + l3 * 2) * HW * HW, rmin3, cmin3, tx0, ty0, tid);
    __syncthreads();
    phaseB<K4, S4>(V4, feat, (const float2*)table + (size_t)l4 * TSIZE, tid);
    __syncthreads();
    phaseC<K4>(feat, out + ((size_t)b * 32 + l4 * 2) * HW * HW, rmin4, cmin4, tx0, ty0, tid);
}

// Single level (level 12, K=2).
template<int K>
__device__ __forceinline__ void do_tile(
        const int lvl, const int b, const int tx0, const int ty0,
        const float* __restrict__ x, const float* __restrict__ table,
        float* __restrict__ out, uint32_t* lds) {
    constexpr int S = padS(32 + K);
    constexpr float s = (float)(513 - K) * (1.0f / 512.0f);
    const float nf = (float)c_n[lvl];
    const int tid = threadIdx.x;
    const float* xb0 = x + (size_t)b * 2 * HW * HW;
    const float* xb1 = xb0 + HW * HW;
    uint32_t* V   = lds;
    float2*  feat = (float2*)(lds + 33 * S);

    const int rmin = max((int)floorf(((float)ty0 + 0.5f) * s - 0.5f), 0);
    const int cmin = max((int)floorf(((float)tx0 + 0.5f) * s - 0.5f), 0);
    {
        const int wv = __builtin_amdgcn_readfirstlane(tid >> 6);
        const int c  = tid & 63;
        const int r0 = 8 * wv;
        const int xx = min(cmin + c, HW - 1);
        const int ybase = rmin + r0;
        float v0[K + 8], v1[K + 8];
#pragma unroll
        for (int t = 0; t < K + 8; ++t) {
            const int yy = min(ybase + t, HW - 1);
            v0[t] = (xb0 + yy * HW)[xx];
            v1[t] = (xb1 + yy * HW)[xx];
        }
        vchain<K, K, S>(v0, v1, nf, V, c, r0, 0, 0);
    }
    __syncthreads();
    phaseB<K, S>(V, feat, (const float2*)table + (size_t)lvl * TSIZE, tid);
    __syncthreads();
    phaseC<K>(feat, out + ((size_t)b * 32 + lvl * 2) * HW * HW, rmin, cmin, tx0, ty0, tid);
}

// Identity levels 13,14,15 (K=1, s=1 -> bilinear is identity): x loaded once.
__device__ __forceinline__ void identity3(
        const int b, const int tx0, const int ty0,
        const float* __restrict__ x, const float* __restrict__ table,
        float* __restrict__ out) {
    const int tid = threadIdx.x;
    const int oy = tid >> 3, xo = tx0 + (tid & 7) * 4;
    const int y = ty0 + oy;
    const float* xb0 = x + (size_t)b * 2 * HW * HW;
    const float* xb1 = xb0 + HW * HW;
    const float4 v0 = *(const float4*)&xb0[y * HW + xo];
    const float4 v1 = *(const float4*)&xb1[y * HW + xo];
    const size_t o = (size_t)y * HW + xo;
#pragma unroll
    for (int li = 0; li < 3; ++li) {
        const int lvl = 13 + li;
        const float nf = (float)c_n[13 + li];
        const float2* tb = (const float2*)table + (size_t)lvl * TSIZE;
        float* ob = out + ((size_t)b * 32 + lvl * 2) * HW * HW;
        const uint32_t i0 = (((uint32_t)(v0.x * nf)) ^ (((uint32_t)(v1.x * nf)) * 2654435761u)) & (TSIZE - 1);
        const uint32_t i1 = (((uint32_t)(v0.y * nf)) ^ (((uint32_t)(v1.y * nf)) * 2654435761u)) & (TSIZE - 1);
        const uint32_t i2 = (((uint32_t)(v0.z * nf)) ^ (((uint32_t)(v1.z * nf)) * 2654435761u)) & (TSIZE - 1);
        const uint32_t i3 = (((uint32_t)(v0.w * nf)) ^ (((uint32_t)(v1.w * nf)) * 2654435761u)) & (TSIZE - 1);
        const float2 f0 = tb[i0], f1 = tb[i1], f2 = tb[i2], f3 = tb[i3];
        const vfloat4 o0 = (vfloat4){f0.x, f1.x, f2.x, f3.x};
        const vfloat4 o1 = (vfloat4){f0.y, f1.y, f2.y, f3.y};
        __builtin_nontemporal_store(o0, (vfloat4*)&ob[o]);
        __builtin_nontemporal_store(o1, (vfloat4*)&ob[o + (size_t)HW * HW]);
    }
}

// Grid: bid = group*2048 + tile*8 + b (b fastest -> batch pinned to XCD;
// heavy quad first, identity fills the tail). 5 groups x 256 tiles x 8 b.
__global__ __launch_bounds__(256) void fused_kernel(
        const float* __restrict__ x, const float* __restrict__ table,
        float* __restrict__ out) {
    // max group LDS: G0 = 33*(68+60+52+52) + 33*34*2 = 9900 dw = 39600 B
    __shared__ __align__(16) uint32_t lds[9900];

    const int bid  = blockIdx.x;
    const int b    = bid & 7;
    const int tile = (bid >> 3) & 255;
    const int grp  = bid >> 11;            // 0..4
    const int tx0  = (tile & 15) * 32;
    const int ty0  = (tile >> 4) * 32;

    switch (grp) {
        case 0: do_quad<32,25,20,16>( 0,  1,  2,  3, b, tx0, ty0, x, table, out, lds); break;
        case 1: do_quad<12,10, 8, 6>( 4,  5,  6,  7, b, tx0, ty0, x, table, out, lds); break;
        case 2: do_quad< 5, 4, 3, 2>( 8,  9, 10, 11, b, tx0, ty0, x, table, out, lds); break;
        case 3: do_tile<2>(12, b, tx0, ty0, x, table, out, lds); break;
        default: identity3(b, tx0, ty0, x, table, out); break;
    }
}

extern "C" void kernel_launch(void* const* d_in, const int* in_sizes, int n_in,
                              void* d_out, int out_size, void* d_ws, size_t ws_size,
                              hipStream_t stream) {
    const float* x     = (const float*)d_in[0];
    const float* table = (const float*)d_in[1];
    float* out         = (float*)d_out;
    (void)d_ws; (void)ws_size;

    fused_kernel<<<dim3(5 * 256 * 8), dim3(256), 0, stream>>>(x, table, out);
}

// Round 22
// 105.464 us; speedup vs baseline: 1.0973x; 1.0973x over previous
//
#include <hip/hip_runtime.h>
#include <stdint.h>

#define NLVL 16
#define TSIZE 16384
#define HW 512

typedef float vfloat4 __attribute__((ext_vector_type(4)));  // native vec for nt-store

__constant__ int c_n[NLVL] = {16,20,25,32,40,50,64,80,101,128,161,203,256,322,406,512};

__device__ __forceinline__ uint32_t pkmax(uint32_t a, uint32_t b) {
    uint32_t r;
    asm("v_pk_max_u16 %0, %1, %2" : "=v"(r) : "v"(a), "v"(b));
    return r;
}

// V stride: pad cols to multiple of 4 with stride % 8 == 4 (banks spread over
// rows; avoids the stride%32==0 16-way conflict class).
constexpr int padS(int w) {
    int s = (w + 3) & ~3;
    if (s % 8 == 0) s += 4;
    return s;
}

// P sliding-window (width KK) maxima: o[j] = max(e[j..j+KK-1]).
// Block van Herk: per KK-output block, suffix array (KK regs) + running max.
template<int KK, int P, int NE>
__device__ __forceinline__ void winmax(const uint32_t (&e)[NE], uint32_t (&o)[P]) {
    static_assert(NE >= P + KK - 1, "window overrun");
    if constexpr (KK == 1) {
#pragma unroll
        for (int j = 0; j < P; ++j) o[j] = e[j];
    } else {
        constexpr int NB = (P + KK - 1) / KK;
#pragma unroll
        for (int bb = 0; bb < NB; ++bb) {
            const int j0 = bb * KK;
            uint32_t sfx[KK];
            sfx[KK - 1] = e[j0 + KK - 1];
#pragma unroll
            for (int t = KK - 2; t >= 0; --t) sfx[t] = pkmax(e[j0 + t], sfx[t + 1]);
            o[j0] = sfx[0];
            uint32_t run = 0;
#pragma unroll
            for (int d = 1; d < KK; ++d) {
                if (j0 + d < P) {
                    run = (d == 1) ? e[j0 + KK] : pkmax(run, e[j0 + KK + d - 1]);
                    o[j0 + d] = pkmax(sfx[d], run);
                }
            }
        }
    }
}

// Vertical chain for one level inside a shared-load group: pack loaded floats
// with this level's nf, window-max, write to its V plane at shifted (dr,dc).
template<int K1, int Ki, int Si>
__device__ __forceinline__ void vchain(const float (&v0)[K1 + 8], const float (&v1)[K1 + 8],
                                       const float nfi, uint32_t* __restrict__ Vi,
                                       const int c, const int r0,
                                       const int dri, const int dci) {
    constexpr int Pi = K1 - Ki + 9;
    uint32_t e[K1 + 8];
#pragma unroll
    for (int t = 0; t < K1 + 8; ++t)
        e[t] = (uint32_t)(v0[t] * nfi) | ((uint32_t)(v1[t] * nfi) << 16);
    uint32_t o[Pi];
    winmax<Ki, Pi, K1 + 8>(e, o);
    const int ci = c - dci;
    if (ci >= 0 && ci < Si) {
#pragma unroll
        for (int j = 0; j < Pi; ++j) {
            const int i2 = r0 + j - dri;
            if (i2 >= 0 && i2 <= 32) Vi[i2 * Si + ci] = o[j];   // wave dups: same value
        }
    }
}

// Horizontal window-max + hash + gather: V[33][S] packed -> feat[33][34].
template<int K, int S>
__device__ __forceinline__ void phaseB(const uint32_t* __restrict__ V,
                                       float2* __restrict__ feat,
                                       const float2* __restrict__ tb, const int tid) {
    if (tid < 99) {
        const int i = tid / 3, g = tid % 3;
        constexpr int NCH = (K + 14) >> 2;
        uint32_t f[NCH * 4];
        const uint4* rp = (const uint4*)(V + i * S + 12 * g);    // 16B aligned (S%4==0)
#pragma unroll
        for (int cc = 0; cc < NCH; ++cc) {
            const uint4 q = rp[cc];
            f[4*cc] = q.x; f[4*cc+1] = q.y; f[4*cc+2] = q.z; f[4*cc+3] = q.w;
        }
        uint32_t wm[12];
        winmax<K, 12, NCH * 4>(f, wm);
#pragma unroll
        for (int d = 0; d < 12; ++d) {
            const int j = 12 * g + d;
            if (j < 33) {
                const uint32_t m = wm[d];
                const uint32_t idx = ((m & 0xFFFFu) ^ ((m >> 16) * 2654435761u)) & (TSIZE - 1);
                feat[i * 34 + j] = tb[idx];
            }
        }
    }
}

// Bilinear interp from feat + nt stores.
template<int K>
__device__ __forceinline__ void phaseC(const float2* __restrict__ feat,
                                       float* __restrict__ ob,
                                       const int rmin, const int cmin,
                                       const int tx0, const int ty0, const int tid) {
    constexpr int gh = 513 - K;
    constexpr float s = (float)gh * (1.0f / 512.0f);
    const int bty = tid >> 5, btx = tid & 31;
    const int xo = tx0 + btx;
    const float sxf = ((float)xo + 0.5f) * s - 0.5f;
    const float fxf = floorf(sxf);
    const float wx = sxf - fxf;
    const int x0i = (int)fxf;
    const int jx0 = min(max(x0i, 0), gh - 1) - cmin;
    const int jx1 = min(max(x0i + 1, 0), gh - 1) - cmin;
    for (int oy = bty; oy < 32; oy += 8) {
        const int y = ty0 + oy;
        const float syf = ((float)y + 0.5f) * s - 0.5f;
        const float fyf = floorf(syf);
        const float wy = syf - fyf;
        const int y0i = (int)fyf;
        const int iy0 = min(max(y0i, 0), gh - 1) - rmin;
        const int iy1 = min(max(y0i + 1, 0), gh - 1) - rmin;
        const float2 f00 = feat[iy0 * 34 + jx0], f01 = feat[iy0 * 34 + jx1];
        const float2 f10 = feat[iy1 * 34 + jx0], f11 = feat[iy1 * 34 + jx1];
        const float w11 = wy * wx;
        const float w10 = wy - w11;
        const float w01 = wx - w11;
        const float w00 = 1.0f - wy - wx + w11;
        const float c0 = f00.x * w00 + f01.x * w01 + f10.x * w10 + f11.x * w11;
        const float c1 = f00.y * w00 + f01.y * w01 + f10.y * w10 + f11.y * w11;
        const size_t o = (size_t)y * HW + xo;
        __builtin_nontemporal_store(c0, &ob[o]);
        __builtin_nontemporal_store(c1, &ob[o + (size_t)HW * HW]);
    }
}

// TWO levels from ONE loaded register strip (proven R20 structure).
template<int K1, int K2>
__device__ __forceinline__ void do_pair(
        const int l1, const int l2, const int b, const int tx0, const int ty0,
        const float* __restrict__ x, const float* __restrict__ table,
        float* __restrict__ out, uint32_t* lds) {
    constexpr int S1 = padS(32 + K1), S2 = padS(32 + K2);
    constexpr float s1 = (float)(513 - K1) * (1.0f / 512.0f);
    constexpr float s2 = (float)(513 - K2) * (1.0f / 512.0f);
    const int tid = threadIdx.x;

    uint32_t* V1 = lds;
    uint32_t* V2 = V1 + 33 * S1;
    float2*  feat = (float2*)(V2 + 33 * S2);

    const float* xb0 = x + (size_t)b * 2 * HW * HW;
    const float* xb1 = xb0 + HW * HW;

    const int rmin1 = max((int)floorf(((float)ty0 + 0.5f) * s1 - 0.5f), 0);
    const int cmin1 = max((int)floorf(((float)tx0 + 0.5f) * s1 - 0.5f), 0);
    const int rmin2 = max((int)floorf(((float)ty0 + 0.5f) * s2 - 0.5f), 0);
    const int cmin2 = max((int)floorf(((float)tx0 + 0.5f) * s2 - 0.5f), 0);

    {
        const int wv = __builtin_amdgcn_readfirstlane(tid >> 6);
        const int c  = tid & 63;
        const int r0 = 8 * wv;
        const int xx = min(cmin1 + c, HW - 1);
        const int ybase = rmin1 + r0;
        float v0[K1 + 8], v1[K1 + 8];
#pragma unroll
        for (int t = 0; t < K1 + 8; ++t) {
            const int yy = min(ybase + t, HW - 1);
            v0[t] = (xb0 + yy * HW)[xx];
            v1[t] = (xb1 + yy * HW)[xx];
        }
        vchain<K1, K1, S1>(v0, v1, (float)c_n[l1], V1, c, r0, 0, 0);
        vchain<K1, K2, S2>(v0, v1, (float)c_n[l2], V2, c, r0, rmin2 - rmin1, cmin2 - cmin1);
    }
    __syncthreads();

    phaseB<K1, S1>(V1, feat, (const float2*)table + (size_t)l1 * TSIZE, tid);
    __syncthreads();
    phaseC<K1>(feat, out + ((size_t)b * 32 + l1 * 2) * HW * HW, rmin1, cmin1, tx0, ty0, tid);
    __syncthreads();
    phaseB<K2, S2>(V2, feat, (const float2*)table + (size_t)l2 * TSIZE, tid);
    __syncthreads();
    phaseC<K2>(feat, out + ((size_t)b * 32 + l2 * 2) * HW * HW, rmin2, cmin2, tx0, ty0, tid);
}

// THREE levels from ONE loaded register strip (small K only: LDS stays small).
template<int K1, int K2, int K3>
__device__ __forceinline__ void do_tri(
        const int l1, const int l2, const int l3,
        const int b, const int tx0, const int ty0,
        const float* __restrict__ x, const float* __restrict__ table,
        float* __restrict__ out, uint32_t* lds) {
    constexpr int S1 = padS(32 + K1), S2 = padS(32 + K2), S3 = padS(32 + K3);
    constexpr float s1 = (float)(513 - K1) * (1.0f / 512.0f);
    constexpr float s2 = (float)(513 - K2) * (1.0f / 512.0f);
    constexpr float s3 = (float)(513 - K3) * (1.0f / 512.0f);
    const int tid = threadIdx.x;

    uint32_t* V1 = lds;
    uint32_t* V2 = V1 + 33 * S1;
    uint32_t* V3 = V2 + 33 * S2;
    float2*  feat = (float2*)(V3 + 33 * S3);

    const float* xb0 = x + (size_t)b * 2 * HW * HW;
    const float* xb1 = xb0 + HW * HW;

    const int rmin1 = max((int)floorf(((float)ty0 + 0.5f) * s1 - 0.5f), 0);
    const int cmin1 = max((int)floorf(((float)tx0 + 0.5f) * s1 - 0.5f), 0);
    const int rmin2 = max((int)floorf(((float)ty0 + 0.5f) * s2 - 0.5f), 0);
    const int cmin2 = max((int)floorf(((float)tx0 + 0.5f) * s2 - 0.5f), 0);
    const int rmin3 = max((int)floorf(((float)ty0 + 0.5f) * s3 - 0.5f), 0);
    const int cmin3 = max((int)floorf(((float)tx0 + 0.5f) * s3 - 0.5f), 0);

    {
        const int wv = __builtin_amdgcn_readfirstlane(tid >> 6);
        const int c  = tid & 63;
        const int r0 = 8 * wv;
        const int xx = min(cmin1 + c, HW - 1);
        const int ybase = rmin1 + r0;
        float v0[K1 + 8], v1[K1 + 8];
#pragma unroll
        for (int t = 0; t < K1 + 8; ++t) {
            const int yy = min(ybase + t, HW - 1);
            v0[t] = (xb0 + yy * HW)[xx];
            v1[t] = (xb1 + yy * HW)[xx];
        }
        vchain<K1, K1, S1>(v0, v1, (float)c_n[l1], V1, c, r0, 0, 0);
        vchain<K1, K2, S2>(v0, v1, (float)c_n[l2], V2, c, r0, rmin2 - rmin1, cmin2 - cmin1);
        vchain<K1, K3, S3>(v0, v1, (float)c_n[l3], V3, c, r0, rmin3 - rmin1, cmin3 - cmin1);
    }
    __syncthreads();

    phaseB<K1, S1>(V1, feat, (const float2*)table + (size_t)l1 * TSIZE, tid);
    __syncthreads();
    phaseC<K1>(feat, out + ((size_t)b * 32 + l1 * 2) * HW * HW, rmin1, cmin1, tx0, ty0, tid);
    __syncthreads();
    phaseB<K2, S2>(V2, feat, (const float2*)table + (size_t)l2 * TSIZE, tid);
    __syncthreads();
    phaseC<K2>(feat, out + ((size_t)b * 32 + l2 * 2) * HW * HW, rmin2, cmin2, tx0, ty0, tid);
    __syncthreads();
    phaseB<K3, S3>(V3, feat, (const float2*)table + (size_t)l3 * TSIZE, tid);
    __syncthreads();
    phaseC<K3>(feat, out + ((size_t)b * 32 + l3 * 2) * HW * HW, rmin3, cmin3, tx0, ty0, tid);
}

// Identity levels 13,14,15 (K=1, s=1 -> bilinear is identity): x loaded once.
__device__ __forceinline__ void identity3(
        const int b, const int tx0, const int ty0,
        const float* __restrict__ x, const float* __restrict__ table,
        float* __restrict__ out) {
    const int tid = threadIdx.x;
    const int oy = tid >> 3, xo = tx0 + (tid & 7) * 4;
    const int y = ty0 + oy;
    const float* xb0 = x + (size_t)b * 2 * HW * HW;
    const float* xb1 = xb0 + HW * HW;
    const float4 v0 = *(const float4*)&xb0[y * HW + xo];
    const float4 v1 = *(const float4*)&xb1[y * HW + xo];
    const size_t o = (size_t)y * HW + xo;
#pragma unroll
    for (int li = 0; li < 3; ++li) {
        const int lvl = 13 + li;
        const float nf = (float)c_n[13 + li];
        const float2* tb = (const float2*)table + (size_t)lvl * TSIZE;
        float* ob = out + ((size_t)b * 32 + lvl * 2) * HW * HW;
        const uint32_t i0 = (((uint32_t)(v0.x * nf)) ^ (((uint32_t)(v1.x * nf)) * 2654435761u)) & (TSIZE - 1);
        const uint32_t i1 = (((uint32_t)(v0.y * nf)) ^ (((uint32_t)(v1.y * nf)) * 2654435761u)) & (TSIZE - 1);
        const uint32_t i2 = (((uint32_t)(v0.z * nf)) ^ (((uint32_t)(v1.z * nf)) * 2654435761u)) & (TSIZE - 1);
        const uint32_t i3 = (((uint32_t)(v0.w * nf)) ^ (((uint32_t)(v1.w * nf)) * 2654435761u)) & (TSIZE - 1);
        const float2 f0 = tb[i0], f1 = tb[i1], f2 = tb[i2], f3 = tb[i3];
        const vfloat4 o0 = (vfloat4){f0.x, f1.x, f2.x, f3.x};
        const vfloat4 o1 = (vfloat4){f0.y, f1.y, f2.y, f3.y};
        __builtin_nontemporal_store(o0, (vfloat4*)&ob[o]);
        __builtin_nontemporal_store(o1, (vfloat4*)&ob[o + (size_t)HW * HW]);
    }
}

// Grid: bid = group*2048 + tile*8 + b (b fastest -> batch pinned to XCD;
// heavy groups dispatch first). 6 groups x 256 tiles x 8 batches.
// Groups: P(32,25) P(20,16) T(12,10,8) T(6,5,4) T(3,2,2) identity3
// -> total phase-A row loads 113 vs 138 (R20 pairs), LDS max 26.4 KB (= R20).
__global__ __launch_bounds__(256) void fused_kernel(
        const float* __restrict__ x, const float* __restrict__ table,
        float* __restrict__ out) {
    // max group LDS: T(12,10,8) = 33*(44+44+44) + 33*34*2 = 6600 dw = 26400 B
    __shared__ __align__(16) uint32_t lds[6600];

    const int bid  = blockIdx.x;
    const int b    = bid & 7;
    const int tile = (bid >> 3) & 255;
    const int grp  = bid >> 11;            // 0..5
    const int tx0  = (tile & 15) * 32;
    const int ty0  = (tile >> 4) * 32;

    switch (grp) {
        case 0: do_pair<32,25>( 0,  1, b, tx0, ty0, x, table, out, lds); break;
        case 1: do_pair<20,16>( 2,  3, b, tx0, ty0, x, table, out, lds); break;
        case 2: do_tri<12,10,8>( 4,  5,  6, b, tx0, ty0, x, table, out, lds); break;
        case 3: do_tri< 6, 5,4>( 7,  8,  9, b, tx0, ty0, x, table, out, lds); break;
        case 4: do_tri< 3, 2,2>(10, 11, 12, b, tx0, ty0, x, table, out, lds); break;
        default: identity3(b, tx0, ty0, x, table, out); break;
    }
}

extern "C" void kernel_launch(void* const* d_in, const int* in_sizes, int n_in,
                              void* d_out, int out_size, void* d_ws, size_t ws_size,
                              hipStream_t stream) {
    const float* x     = (const float*)d_in[0];
    const float* table = (const float*)d_in[1];
    float* out         = (float*)d_out;
    (void)d_ws; (void)ws_size;

    fused_kernel<<<dim3(6 * 256 * 8), dim3(256), 0, stream>>>(x, table, out);
}